// Round 6
// baseline (192.490 us; speedup 1.0000x reference)
//
#include <hip/hip_runtime.h>
#include <hip/hip_bf16.h>
#include <cstdint>

#define B_ 8
#define N_ 256
#define CS_ 512
#define H_ 8
#define D_ 64
#define K_ 32
#define NB_ 65
#define CT_ 2048
#define WL_ 0.70710678118654752f

typedef __attribute__((ext_vector_type(8))) short bf16x8;
typedef __attribute__((ext_vector_type(4))) float f32x4;

#define GLOBAL_AS __attribute__((address_space(1)))
#define LDS_AS __attribute__((address_space(3)))

__device__ __forceinline__ void async16(void* lds, const void* g) {
  __builtin_amdgcn_global_load_lds((const GLOBAL_AS uint32_t*)g,
                                   (LDS_AS uint32_t*)lds, 16, 0, 0);
}

__device__ __forceinline__ ushort f2bf(float v) {
  __hip_bfloat16 hb = __float2bfloat16(v);
  return *(ushort*)&hb;
}

__device__ __forceinline__ float bf2f(ushort u) {
  union { uint32_t ui; float f; } cv; cv.ui = (uint32_t)u << 16;
  return cv.f;
}

// ------------- GEMM with NATIVE f32 weight B: C = A[M,K] @ W[K<=Kd,N] -----
// 64x64 tile, 128 threads (2 waves, wave = 32 rows x 64 cols), dbuf LDS.
// A: bf16 [M,Kd] via global_load_lds (validated path). B: f32 W rows staged
// reg->cvt->swizzled LDS (transpose-in-kernel; kills the prep transposes).
// Rows k >= Kw read as 0 (wo pad). flags: 1=+bias (z==0), 2=relu,
// 32=offset bf16 out by z*M*Nc (split-K partials). Output always bf16 blast.
__global__ __launch_bounds__(128, 2) void gemm_wf32(
    const ushort* __restrict__ A, const float* __restrict__ W,
    const float* __restrict__ bias, ushort* __restrict__ Cb,
    int M, int Nc, int Kd, int Kw, int flags) {
  __shared__ ushort As[2][64 * 64];   // 16 KB (buf 0 reused as bounce)
  __shared__ ushort Bs[2][64 * 64];   // 16 KB
  int tid = threadIdx.x;
  int bm = blockIdx.y * 64, bn = blockIdx.x * 64;
  int S = gridDim.z, z = blockIdx.z;
  int T = Kd >> 6;
  int it0 = (z * T) / S, it1 = ((z + 1) * T) / S;
  if (flags & 32) Cb += (size_t)z * M * Nc;
  int w = tid >> 6, l = tid & 63;
  int lm = l & 15, lq = l >> 4;
  int srow = tid >> 3, sg = tid & 7;    // A staging
  int n4 = tid & 15, kpr = tid >> 4;    // B staging: n-quad, k-pair base

  f32x4 acc[2][4];
#pragma unroll
  for (int i = 0; i < 2; ++i)
#pragma unroll
    for (int j = 0; j < 4; ++j) acc[i][j] = (f32x4){0.f, 0.f, 0.f, 0.f};

  float4 br0[4], br1[4];
  // ---- helpers expanded inline ----
#define STAGE_A(buf, itx)                                                    \
  {                                                                          \
    int k0 = (itx) << 6;                                                     \
    _Pragma("unroll") for (int r = 0; r < 4; ++r) {                          \
      int row = r * 16 + srow;                                               \
      int gl = sg ^ (row & 7);                                               \
      async16(&As[buf][row * 64 + sg * 8],                                   \
              A + (size_t)(bm + row) * Kd + k0 + gl * 8);                    \
    }                                                                        \
  }
#define LOAD_B(itx)                                                          \
  {                                                                          \
    int k0 = (itx) << 6;                                                     \
    _Pragma("unroll") for (int r = 0; r < 4; ++r) {                          \
      int kp = kpr + r * 8;                                                  \
      int k = k0 + 2 * kp;                                                   \
      const float* p = W + (size_t)k * Nc + bn + n4 * 4;                     \
      br0[r] = (k < Kw) ? *(const float4*)p : (float4){0.f, 0.f, 0.f, 0.f};  \
      br1[r] = (k + 1 < Kw) ? *(const float4*)(p + Nc)                       \
                            : (float4){0.f, 0.f, 0.f, 0.f};                  \
    }                                                                        \
  }
#define WRITE_B(buf)                                                         \
  {                                                                          \
    _Pragma("unroll") for (int r = 0; r < 4; ++r) {                          \
      int kp = kpr + r * 8;                                                  \
      int kg = kp >> 2;                                                      \
      _Pragma("unroll") for (int i = 0; i < 4; ++i) {                        \
        int n = n4 * 4 + i;                                                  \
        uint32_t v = (uint32_t)f2bf(((const float*)&br0[r])[i]) |            \
                     ((uint32_t)f2bf(((const float*)&br1[r])[i]) << 16);     \
        *(uint32_t*)((char*)&Bs[buf][0] + n * 128 +                          \
                     ((kg ^ (n & 7)) << 4) + (kp & 3) * 4) = v;              \
      }                                                                      \
    }                                                                        \
  }

  // prologue: A async into buf0; B loads -> cvt -> buf0 (no readers yet)
  STAGE_A(0, it0);
  LOAD_B(it0);
  WRITE_B(0);

  for (int it = it0; it < it1; ++it) {
    int cur = (it - it0) & 1;
    int nxt = cur ^ 1;
    __syncthreads();   // A(cur) asyncs drained; B(cur) writes visible;
                       // readers of nxt (prev iter) done
    bool pf = (it + 1 < it1);
    if (pf) {
      STAGE_A(nxt, it + 1);
      LOAD_B(it + 1);   // reg loads land under the MFMA phase below
    }
#pragma unroll
    for (int kk = 0; kk < 2; ++kk) {
      bf16x8 af[2], bfr[4];
#pragma unroll
      for (int i = 0; i < 2; ++i) {
        int ma = w * 32 + 16 * i + lm;
        af[i] = *(const bf16x8*)&As[cur][ma * 64 + ((kk * 4 + lq) ^ (ma & 7)) * 8];
      }
#pragma unroll
      for (int j = 0; j < 4; ++j) {
        int nb = 16 * j + lm;
        bfr[j] = *(const bf16x8*)&Bs[cur][nb * 64 + ((kk * 4 + lq) ^ (nb & 7)) * 8];
      }
#pragma unroll
      for (int i = 0; i < 2; ++i)
#pragma unroll
        for (int j = 0; j < 4; ++j)
          acc[i][j] = __builtin_amdgcn_mfma_f32_16x16x32_bf16(
              af[i], bfr[j], acc[i][j], 0, 0, 0);
    }
    if (pf) WRITE_B(nxt);   // nxt's readers finished before this iter's barrier
  }
  __syncthreads();   // all waves done with LDS before bounce reuse

  int lr = l >> 3, lc = l & 7;       // blast: 8 lanes per 128B row
  ushort* Tb = &As[0][0] + w * 2048; // wave-private 4 KB bounce

#pragma unroll
  for (int j = 0; j < 4; ++j) {
    float bv = ((flags & 1) && z == 0) ? bias[bn + 16 * j + lm] : 0.f;
#pragma unroll
    for (int i = 0; i < 2; ++i)
#pragma unroll
      for (int r = 0; r < 4; ++r) {
        float v = acc[i][j][r] + bv;
        if (flags & 2) v = fmaxf(v, 0.f);
        Tb[(16 * i + lq * 4 + r) * 64 + 16 * j + lm] = f2bf(v);
      }
  }
  __asm__ __volatile__("" ::: "memory");
#pragma unroll
  for (int p = 0; p < 4; ++p) {
    int rowL = p * 8 + lr;
    bf16x8 vv = *(const bf16x8*)&Tb[rowL * 64 + lc * 8];
    *(bf16x8*)(Cb + (size_t)(bm + w * 32 + rowL) * Nc + bn + lc * 8) = vv;
  }
#undef STAGE_A
#undef LOAD_B
#undef WRITE_B
}

// ---------------- QKV GEMM (bf16 A and B^T, head-layout epilogue) ---------
// 768 blocks of 64x64; validated R5 path, transpose branch removed.
__global__ __launch_bounds__(128, 2) void qkv_gemm(
    const ushort* __restrict__ A, const ushort* __restrict__ Bt,
    ushort* __restrict__ Cb) {
  __shared__ __align__(16) ushort As[2][64 * 64];   // 16 KB
  __shared__ ushort Bs[2][64 * 64];                 // 16 KB
  int blk = blockIdx.x, tid = threadIdx.x;
  int bm = (blk / 24) * 64, bn = (blk % 24) * 64;
  const int Kd = 512, it1 = 8;
  int w = tid >> 6, l = tid & 63;
  int lm = l & 15, lq = l >> 4;
  int srow = tid >> 3;
  int sg = tid & 7;

  f32x4 acc[2][4];
#pragma unroll
  for (int i = 0; i < 2; ++i)
#pragma unroll
    for (int j = 0; j < 4; ++j) acc[i][j] = (f32x4){0.f, 0.f, 0.f, 0.f};

  {
#pragma unroll
    for (int r = 0; r < 4; ++r) {
      int row = r * 16 + srow;
      int gl = sg ^ (row & 7);
      async16(&As[0][row * 64 + sg * 8],
              A + (size_t)(bm + row) * Kd + gl * 8);
      async16(&Bs[0][row * 64 + sg * 8],
              Bt + (size_t)(bn + row) * Kd + gl * 8);
    }
  }
  for (int it = 0; it < it1; ++it) {
    int cur = it & 1;
    __syncthreads();
    if (it + 1 < it1) {
      int nxt = cur ^ 1;
      int k0 = (it + 1) << 6;
#pragma unroll
      for (int r = 0; r < 4; ++r) {
        int row = r * 16 + srow;
        int gl = sg ^ (row & 7);
        async16(&As[nxt][row * 64 + sg * 8],
                A + (size_t)(bm + row) * Kd + k0 + gl * 8);
        async16(&Bs[nxt][row * 64 + sg * 8],
                Bt + (size_t)(bn + row) * Kd + k0 + gl * 8);
      }
    }
#pragma unroll
    for (int kk = 0; kk < 2; ++kk) {
      bf16x8 af[2], bfr[4];
#pragma unroll
      for (int i = 0; i < 2; ++i) {
        int ma = w * 32 + 16 * i + lm;
        af[i] = *(const bf16x8*)&As[cur][ma * 64 + ((kk * 4 + lq) ^ (ma & 7)) * 8];
      }
#pragma unroll
      for (int j = 0; j < 4; ++j) {
        int nb = 16 * j + lm;
        bfr[j] = *(const bf16x8*)&Bs[cur][nb * 64 + ((kk * 4 + lq) ^ (nb & 7)) * 8];
      }
#pragma unroll
      for (int i = 0; i < 2; ++i)
#pragma unroll
        for (int j = 0; j < 4; ++j)
          acc[i][j] = __builtin_amdgcn_mfma_f32_16x16x32_bf16(
              af[i], bfr[j], acc[i][j], 0, 0, 0);
    }
  }
  __syncthreads();

  int lr = l >> 3, lc = l & 7;
  ushort* Tb = &As[0][0] + w * 2048;   // wave-private 4 KB bounce

  int which = bn >> 9;
  int hh = (bn & 511) >> 6;
  int b = bm >> 8, nn0 = bm & 255;
  if (which == 2) {               // v: transpose to [d][n]; wave n = w*32..+31
#pragma unroll
    for (int j = 0; j < 4; ++j)
#pragma unroll
      for (int i = 0; i < 2; ++i) {
        ushort pk[4];
#pragma unroll
        for (int r = 0; r < 4; ++r) pk[r] = f2bf(acc[i][j][r]);
        *(uint2*)&Tb[(16 * j + lm) * 32 + 16 * i + lq * 4] = *(uint2*)pk;
      }
  } else {                        // q,k: [n][d]; wave rows w*32..+31
#pragma unroll
    for (int j = 0; j < 4; ++j)
#pragma unroll
      for (int i = 0; i < 2; ++i)
#pragma unroll
        for (int r = 0; r < 4; ++r)
          Tb[(16 * i + lq * 4 + r) * 64 + 16 * j + lm] = f2bf(acc[i][j][r]);
  }
  __asm__ __volatile__("" ::: "memory");
  ushort* dstb = Cb + (size_t)which * 1048576 + (size_t)(b * 8 + hh) * 16384;
  if (which == 2) {
    int vr = l >> 2, vc = l & 3;  // 16 d-rows x 4 n-chunks per pass
#pragma unroll
    for (int p = 0; p < 4; ++p) {
      int rowL = p * 16 + vr;     // d
      bf16x8 vv = *(const bf16x8*)&Tb[rowL * 32 + vc * 8];
      *(bf16x8*)(dstb + (size_t)rowL * 256 + nn0 + w * 32 + vc * 8) = vv;
    }
  } else {
#pragma unroll
    for (int p = 0; p < 4; ++p) {
      int rowL = p * 8 + lr;      // n-local 0..31
      bf16x8 vv = *(const bf16x8*)&Tb[rowL * 64 + lc * 8];
      *(bf16x8*)(dstb + (size_t)(nn0 + w * 32 + rowL) * 64 + lc * 8) = vv;
    }
  }
}

// ---------------- prep: s->bf16 + wqkv transpose only ---------------------
__global__ __launch_bounds__(256) void prep_small(
    const float* __restrict__ s, __hip_bfloat16* __restrict__ s_bf,
    const float* __restrict__ wq, const float* __restrict__ wk,
    const float* __restrict__ wv, __hip_bfloat16* __restrict__ wqkvT) {
  int blk = blockIdx.x;
  if (blk < 512) {
    int i = blk * 256 + threadIdx.x;   // 131072 threads x 8 elems
    float4 a = ((const float4*)s)[i * 2];
    float4 c = ((const float4*)s)[i * 2 + 1];
    ushort pk[8] = {f2bf(a.x), f2bf(a.y), f2bf(a.z), f2bf(a.w),
                    f2bf(c.x), f2bf(c.y), f2bf(c.z), f2bf(c.w)};
    *(uint4*)&((ushort*)s_bf)[i * 8] = *(uint4*)pk;
    return;
  }
  int t = blk - 512;
  __shared__ float tile[32][33];
  int zz = t >> 8, tIdx = t & 255;
  const float* src = zz == 0 ? wq : zz == 1 ? wk : wv;
  int whichBase = zz * 512;
  int c0 = (tIdx & 15) * 32, r0 = (tIdx >> 4) * 32;
  int tx = threadIdx.x & 7, ty = threadIdx.x >> 3;   // 8 x 32
  {
    int r = r0 + ty, c = c0 + tx * 4;
    float4 v = *(const float4*)&src[(size_t)r * 512 + c];
    tile[ty][tx * 4 + 0] = v.x;
    tile[ty][tx * 4 + 1] = v.y;
    tile[ty][tx * 4 + 2] = v.z;
    tile[ty][tx * 4 + 3] = v.w;
  }
  __syncthreads();
  {
    int cc = c0 + ty;                 // dst row (source col)
    int k = r0 + tx * 4;              // dst col (source row), 4-chunk
    float a0 = tile[tx * 4 + 0][ty];
    float a1 = tile[tx * 4 + 1][ty];
    float a2 = tile[tx * 4 + 2][ty];
    float a3 = tile[tx * 4 + 3][ty];
    int n = whichBase + (cc & 7) * 64 + (cc >> 3);
    ushort pk[4] = {f2bf(a0), f2bf(a1), f2bf(a2), f2bf(a3)};
    *(uint2*)&((ushort*)wqkvT)[(size_t)n * 512 + k] = *(uint2*)pk;
  }
}

// ---------------- fused attention: QK^T+softmax -> a, PV -> o, o_pair -----
__global__ __launch_bounds__(128) void attn_fused(
    const ushort* __restrict__ qh, const ushort* __restrict__ kh,
    const ushort* __restrict__ vT, const int* __restrict__ masks,
    const float* __restrict__ wb, float* __restrict__ a_out,
    ushort* __restrict__ cat) {
  int strip = blockIdx.x & 7, bh = blockIdx.x >> 3;
  int h = bh & 7, b = bh >> 3;
  __shared__ ushort Ks[256 * 64];   // 32 KB
  __shared__ ushort Ps[32 * 64];    // 4 KB, k-quarter P (wave-private rows)
  __shared__ float wbs[NB_];
  __shared__ float mfj[256];
  int tid = threadIdx.x;
  int srow = tid >> 3, sg = tid & 7;
#pragma unroll
  for (int rr = 0; rr < 16; ++rr) {
    int row = rr * 16 + srow;
    int gl = sg ^ (row & 7);
    async16(&Ks[row * 64 + sg * 8],
            kh + ((size_t)bh * 256 + row) * 64 + gl * 8);
  }
  int w = tid >> 6, l = tid & 63, lm = l & 15, lq = l >> 4;
  bf16x8 qf[2];
  {
    const ushort* qrow =
        qh + ((size_t)bh * 256 + strip * 32 + w * 16 + lm) * 64 + lq * 8;
    qf[0] = *(const bf16x8*)qrow;
    qf[1] = *(const bf16x8*)(qrow + 32);
  }
  if (tid < NB_) wbs[tid] = wb[tid * H_ + h];
  mfj[tid]       = (masks[b * 256 + tid] != 0) ? 1.f : 0.f;
  mfj[tid + 128] = (masks[b * 256 + tid + 128] != 0) ? 1.f : 0.f;
  __syncthreads();   // the only barrier

  f32x4 acc[16];
#pragma unroll
  for (int ct = 0; ct < 16; ++ct) {
    int krow = ct * 16 + lm;
    bf16x8 kf0 = *(const bf16x8*)&Ks[krow * 64 + ((lq) ^ (krow & 7)) * 8];
    bf16x8 kf1 = *(const bf16x8*)&Ks[krow * 64 + ((4 + lq) ^ (krow & 7)) * 8];
    f32x4 zf = (f32x4){0.f, 0.f, 0.f, 0.f};
    zf = __builtin_amdgcn_mfma_f32_16x16x32_bf16(qf[0], kf0, zf, 0, 0, 0);
    acc[ct] = __builtin_amdgcn_mfma_f32_16x16x32_bf16(qf[1], kf1, zf, 0, 0, 0);
  }
  int ibase = strip * 32 + w * 16 + lq * 4;
  float mfi[4];
#pragma unroll
  for (int r = 0; r < 4; ++r) mfi[r] = mfj[ibase + r];
#pragma unroll
  for (int ct = 0; ct < 16; ++ct) {
    int j = ct * 16 + lm;
    float mj = mfj[j];
#pragma unroll
    for (int r = 0; r < 4; ++r) {
      int i = ibase + r;
      int diff = i - j;
      int cb = diff < -K_ ? 0 : (diff > K_ ? 2 * K_ : diff + K_);
      float sq = mfi[r] * mj;
      acc[ct][r] = WL_ * (acc[ct][r] * 0.125f + wbs[cb] * sq) - 1e9f * (1.f - sq);
    }
  }
  float mx[4], sm[4];
#pragma unroll
  for (int r = 0; r < 4; ++r) {
    float m = acc[0][r];
#pragma unroll
    for (int ct = 1; ct < 16; ++ct) m = fmaxf(m, acc[ct][r]);
#pragma unroll
    for (int o = 1; o < 16; o <<= 1) m = fmaxf(m, __shfl_xor(m, o, 64));
    mx[r] = m;
  }
#pragma unroll
  for (int ct = 0; ct < 16; ++ct)
#pragma unroll
    for (int r = 0; r < 4; ++r) acc[ct][r] = __expf(acc[ct][r] - mx[r]);
#pragma unroll
  for (int r = 0; r < 4; ++r) {
    float s = 0.f;
#pragma unroll
    for (int ct = 0; ct < 16; ++ct) s += acc[ct][r];
#pragma unroll
    for (int o = 1; o < 16; o <<= 1) s += __shfl_xor(s, o, 64);
    sm[r] = 1.f / s;
  }
  // ---- a stores (f32) + o_pair into cat (bf16) ----
  float p0[4] = {0.f, 0.f, 0.f, 0.f}, p64[4] = {0.f, 0.f, 0.f, 0.f};
#pragma unroll
  for (int ct = 0; ct < 16; ++ct) {
    int j = ct * 16 + lm;
    float mj = mfj[j];
#pragma unroll
    for (int r = 0; r < 4; ++r) {
      int i = ibase + r;
      float aval = acc[ct][r] * sm[r];
      a_out[((size_t)bh * 256 + i) * 256 + j] = aval;
      float val = aval * mfi[r] * mj;
      int diff = i - j;
      if (diff <= -K_)      p0[r] += val;
      else if (diff >= K_)  p64[r] += val;
      else cat[((size_t)(b * 256 + i)) * 1088 + h * 65 + diff + K_] = f2bf(val);
    }
  }
#pragma unroll
  for (int r = 0; r < 4; ++r)
#pragma unroll
    for (int o = 1; o < 16; o <<= 1) {
      p0[r]  += __shfl_xor(p0[r], o, 64);
      p64[r] += __shfl_xor(p64[r], o, 64);
    }
  if (lm == 0) {
#pragma unroll
    for (int r = 0; r < 4; ++r) {
      int i = ibase + r;
      cat[((size_t)(b * 256 + i)) * 1088 + h * 65 + 0]      = f2bf(p0[r]);
      cat[((size_t)(b * 256 + i)) * 1088 + h * 65 + 2 * K_] = f2bf(p64[r]);
    }
  }
  // interior bins with out-of-range source j -> 0
#pragma unroll
  for (int r = 0; r < 4; ++r) {
    int i = ibase + r;
#pragma unroll
    for (int t = 0; t < 4; ++t) {
      int c = 1 + lm + 16 * t;
      if (c < 64) {
        int j = i - c + K_;
        if (j < 0 || j > 255)
          cat[((size_t)(b * 256 + i)) * 1088 + h * 65 + c] = 0;
      }
    }
  }
  // pad cols 1032..1088 zeroed by h==0 blocks
  if (h == 0) {
    for (int idx = tid; idx < 32 * 56; idx += 128) {
      int r = idx / 56, c = 1032 + (idx - r * 56);
      cat[((size_t)(b * 256 + strip * 32 + r)) * 1088 + c] = 0;
    }
  }
  // ---- PV: o = P @ V over 4 k-quarters; V frags direct from global ----
  f32x4 acc2[4];
#pragma unroll
  for (int nt = 0; nt < 4; ++nt) acc2[nt] = (f32x4){0.f, 0.f, 0.f, 0.f};
  const ushort* vbase = vT + (size_t)bh * 16384;
#pragma unroll
  for (int qt = 0; qt < 4; ++qt) {
    bf16x8 vf0[4], vf1[4];
#pragma unroll
    for (int nt = 0; nt < 4; ++nt) {
      const ushort* vrow = vbase + (size_t)(nt * 16 + lm) * 256 + qt * 64 + lq * 8;
      vf0[nt] = *(const bf16x8*)vrow;
      vf1[nt] = *(const bf16x8*)(vrow + 32);
    }
#pragma unroll
    for (int ctl = 0; ctl < 4; ++ctl) {
      int ct = qt * 4 + ctl;
#pragma unroll
      for (int r = 0; r < 4; ++r) {
        int rowl = w * 16 + lq * 4 + r;
        int g = ctl * 2 + (lm >> 3);
        Ps[rowl * 64 + ((g ^ (rowl & 7)) << 3) + (lm & 7)] =
            f2bf(acc[ct][r] * sm[r]);
      }
    }
    int prow = w * 16 + lm;
#pragma unroll
    for (int kst = 0; kst < 2; ++kst) {
      bf16x8 af = *(const bf16x8*)&Ps[prow * 64 + (((kst * 4 + lq) ^ (prow & 7)) << 3)];
#pragma unroll
      for (int nt = 0; nt < 4; ++nt)
        acc2[nt] = __builtin_amdgcn_mfma_f32_16x16x32_bf16(
            af, kst ? vf1[nt] : vf0[nt], acc2[nt], 0, 0, 0);
    }
  }
#pragma unroll
  for (int nt = 0; nt < 4; ++nt) {
    int d = nt * 16 + lm;
#pragma unroll
    for (int r = 0; r < 4; ++r) {
      int i = ibase + r;
      cat[((size_t)(b * 256 + i)) * 1088 + 520 + h * 64 + d] = f2bf(acc2[nt][r]);
    }
  }
}

// ---------------- out = LayerNorm(x1 + sum_s xp_bf16[s]) * g + b ----------
__global__ __launch_bounds__(128) void ln_sum(
    const float* __restrict__ x1, const ushort* __restrict__ xp,
    int S, int stride, const float* __restrict__ g,
    const float* __restrict__ bta, float* __restrict__ out,
    __hip_bfloat16* __restrict__ out_bf) {
  __shared__ float redA[2], redB[2];
  int row = blockIdx.x, tid = threadIdx.x;
  size_t base = (size_t)row * 512;
  float4 v = *(const float4*)(x1 + base + tid * 4);
  for (int s = 0; s < S; ++s) {
    uint2 p = *(const uint2*)(xp + (size_t)s * stride + base + tid * 4);
    v.x += bf2f((ushort)(p.x & 0xffff));
    v.y += bf2f((ushort)(p.x >> 16));
    v.z += bf2f((ushort)(p.y & 0xffff));
    v.w += bf2f((ushort)(p.y >> 16));
  }
  float su = v.x + v.y + v.z + v.w;
  float sq = v.x * v.x + v.y * v.y + v.z * v.z + v.w * v.w;
#pragma unroll
  for (int o = 32; o > 0; o >>= 1) {
    su += __shfl_xor(su, o, 64);
    sq += __shfl_xor(sq, o, 64);
  }
  int w = tid >> 6;
  if ((tid & 63) == 0) { redA[w] = su; redB[w] = sq; }
  __syncthreads();
  su = redA[0] + redA[1]; sq = redB[0] + redB[1];
  float mean = su * (1.f / 512.f);
  float var = sq * (1.f / 512.f) - mean * mean;
  float inv = rsqrtf(var + 1e-5f);
  float4 gv = *(const float4*)(g + tid * 4);
  float4 bv = *(const float4*)(bta + tid * 4);
  float4 o4;
  o4.x = (v.x - mean) * inv * gv.x + bv.x;
  o4.y = (v.y - mean) * inv * gv.y + bv.y;
  o4.z = (v.z - mean) * inv * gv.z + bv.z;
  o4.w = (v.w - mean) * inv * gv.w + bv.w;
  *(float4*)(out + base + tid * 4) = o4;
  if (out_bf) {
    ushort pk[4] = {f2bf(o4.x), f2bf(o4.y), f2bf(o4.z), f2bf(o4.w)};
    *(uint2*)&((ushort*)out_bf)[base + tid * 4] = *(uint2*)pk;
  }
}

extern "C" void kernel_launch(void* const* d_in, const int* in_sizes, int n_in,
                              void* d_out, int out_size, void* d_ws, size_t ws_size,
                              hipStream_t stream) {
  const float* s     = (const float*)d_in[0];
  const int*   masks = (const int*)d_in[1];
  const float* wq = (const float*)d_in[2];
  const float* wk = (const float*)d_in[3];
  const float* wv = (const float*)d_in[4];
  const float* wb = (const float*)d_in[5];
  const float* wo = (const float*)d_in[6];
  const float* bo = (const float*)d_in[7];
  const float* ln1_g = (const float*)d_in[8];
  const float* ln1_b = (const float*)d_in[9];
  const float* w1 = (const float*)d_in[10];
  const float* b1 = (const float*)d_in[11];
  const float* w2 = (const float*)d_in[12];
  const float* b2 = (const float*)d_in[13];
  const float* ln2_g = (const float*)d_in[14];
  const float* ln2_b = (const float*)d_in[15];

  float* out_x = (float*)d_out;              // [8,256,512]
  float* out_a = out_x + 1048576;            // [8,8,256,256]

  // disjoint workspace (float offsets)
  float* ws = (float*)d_ws;
  ushort* embd_part = (ushort*)(ws + 0);                   // [2][2048,512] bf16
  float* xbuf       = ws + 4194304;
  ushort* ff_part   = (ushort*)(ws + 5242880);             // [2][2048,512] bf16
  ushort* qkv_bf    = (ushort*)(ws + 9437184);             // q|k [B,H,N,D], v [B,H,D,N]
  ushort* q_bf = qkv_bf;
  ushort* k_bf = qkv_bf + 1048576;
  ushort* v_bf = qkv_bf + 2097152;
  ushort* cat_bf = (ushort*)(ws + 10223616);               // [2048,1088]
  __hip_bfloat16* h_bf  = (__hip_bfloat16*)(ws + 11337728);  // [2048,2048]
  __hip_bfloat16* s_bf  = (__hip_bfloat16*)(ws + 13434880);  // [2048,512]
  __hip_bfloat16* x_bf  = (__hip_bfloat16*)(ws + 13959168);  // [2048,512]
  __hip_bfloat16* wqkvT = (__hip_bfloat16*)(ws + 14483456);  // [1536,512]

  dim3 blkg(128);
  // 0. prep: s cvt (512 blocks) + wqkv transpose (768 blocks)
  prep_small<<<dim3(1280), dim3(256), 0, stream>>>(s, s_bf, wq, wk, wv, wqkvT);
  // 1. QKV projection (768 blocks of 64x64) -> head layout
  qkv_gemm<<<dim3(768), blkg, 0, stream>>>(
      (const ushort*)s_bf, (const ushort*)wqkvT, qkv_bf);
  // 2. fused attention: a -> d_out, o + o_pair -> cat_bf  [512 x 128thr]
  attn_fused<<<dim3(512), blkg, 0, stream>>>(q_bf, k_bf, v_bf, masks, wb,
                                             out_a, cat_bf);
  // 3. output projection, NATIVE wo f32 (split-K=2)  [512 blocks]
  gemm_wf32<<<dim3(8, 32, 2), blkg, 0, stream>>>(
      cat_bf, wo, bo, embd_part, 2048, 512, 1088, 1032, 1 | 32);
  // 4. x = LN(s + sum embd_part)
  ln_sum<<<dim3(2048), blkg, 0, stream>>>(s, embd_part, 2, 1048576,
                                          ln1_g, ln1_b, xbuf, x_bf);
  // 5. FFN1, NATIVE w1 f32  [1024 blocks]
  gemm_wf32<<<dim3(32, 32, 1), blkg, 0, stream>>>(
      (const ushort*)x_bf, w1, b1, (ushort*)h_bf, 2048, 2048, 512, 512, 1 | 2);
  // 6. FFN2, NATIVE w2 f32 (split-K=2)  [512 blocks]
  gemm_wf32<<<dim3(8, 32, 2), blkg, 0, stream>>>(
      (const ushort*)h_bf, w2, b2, ff_part, 2048, 512, 2048, 2048, 1 | 32);
  // 7. out = LN(x + sum ff_part)
  ln_sum<<<dim3(2048), blkg, 0, stream>>>(xbuf, ff_part, 2, 1048576,
                                          ln2_g, ln2_b, out_x, nullptr);
}

// Round 8
// 174.967 us; speedup vs baseline: 1.1002x; 1.1002x over previous
//
#include <hip/hip_runtime.h>
#include <hip/hip_bf16.h>
#include <cstdint>

#define B_ 8
#define N_ 256
#define CS_ 512
#define H_ 8
#define D_ 64
#define K_ 32
#define NB_ 65
#define CT_ 2048
#define WL_ 0.70710678118654752f

typedef __attribute__((ext_vector_type(8))) short bf16x8;
typedef __attribute__((ext_vector_type(4))) float f32x4;

#define GLOBAL_AS __attribute__((address_space(1)))
#define LDS_AS __attribute__((address_space(3)))

__device__ __forceinline__ void async16(void* lds, const void* g) {
  __builtin_amdgcn_global_load_lds((const GLOBAL_AS uint32_t*)g,
                                   (LDS_AS uint32_t*)lds, 16, 0, 0);
}

__device__ __forceinline__ ushort f2bf(float v) {
  __hip_bfloat16 hb = __float2bfloat16(v);
  return *(ushort*)&hb;
}

__device__ __forceinline__ float bf2f(ushort u) {
  union { uint32_t ui; float f; } cv; cv.ui = (uint32_t)u << 16;
  return cv.f;
}

// ---------------- bf16 MFMA GEMM: C[M,N] = A[M,K] @ Bt[N,K]^T -------------
// 64x64 tile, 128 threads (2 waves, wave = 32 rows x 64 cols), dbuf LDS.
// flags: 1=+bias[col] (slice 0), 2=relu, 32=offset out by z*M*Nc (split-K).
__global__ __launch_bounds__(128, 2) void gemm_bf16(
    const ushort* __restrict__ A, const ushort* __restrict__ Bt,
    const float* __restrict__ bias, float* __restrict__ C,
    ushort* __restrict__ Cb, int M, int Nc, int Kd, int flags) {
  __shared__ ushort As[2][64 * 64];   // 16 KB (buf reused as epilogue bounce)
  __shared__ ushort Bs[2][64 * 64];   // 16 KB
  int tid = threadIdx.x;
  int bm = blockIdx.y * 64, bn = blockIdx.x * 64;
  int S = gridDim.z, z = blockIdx.z;
  int T = Kd >> 6;
  int it0 = (z * T) / S, it1 = ((z + 1) * T) / S;
  if (flags & 32) Cb += (size_t)z * M * Nc;
  int w = tid >> 6, l = tid & 63;
  int lm = l & 15, lq = l >> 4;
  int srow = tid >> 3;       // 0..15
  int sg = tid & 7;

  f32x4 acc[2][4];
#pragma unroll
  for (int i = 0; i < 2; ++i)
#pragma unroll
    for (int j = 0; j < 4; ++j) acc[i][j] = (f32x4){0.f, 0.f, 0.f, 0.f};

  {
    int k0 = it0 << 6;
#pragma unroll
    for (int r = 0; r < 4; ++r) {
      int row = r * 16 + srow;
      int gl = sg ^ (row & 7);
      async16(&As[0][row * 64 + sg * 8],
              A + (size_t)(bm + row) * Kd + k0 + gl * 8);
      async16(&Bs[0][row * 64 + sg * 8],
              Bt + (size_t)(bn + row) * Kd + k0 + gl * 8);
    }
  }
  for (int it = it0; it < it1; ++it) {
    int cur = (it - it0) & 1;
    __syncthreads();
    if (it + 1 < it1) {
      int nxt = cur ^ 1;
      int k0 = (it + 1) << 6;
#pragma unroll
      for (int r = 0; r < 4; ++r) {
        int row = r * 16 + srow;
        int gl = sg ^ (row & 7);
        async16(&As[nxt][row * 64 + sg * 8],
                A + (size_t)(bm + row) * Kd + k0 + gl * 8);
        async16(&Bs[nxt][row * 64 + sg * 8],
                Bt + (size_t)(bn + row) * Kd + k0 + gl * 8);
      }
    }
#pragma unroll
    for (int kk = 0; kk < 2; ++kk) {
      bf16x8 af[2], bfr[4];
#pragma unroll
      for (int i = 0; i < 2; ++i) {
        int ma = w * 32 + 16 * i + lm;
        af[i] = *(const bf16x8*)&As[cur][ma * 64 + ((kk * 4 + lq) ^ (ma & 7)) * 8];
      }
#pragma unroll
      for (int j = 0; j < 4; ++j) {
        int nb = 16 * j + lm;
        bfr[j] = *(const bf16x8*)&Bs[cur][nb * 64 + ((kk * 4 + lq) ^ (nb & 7)) * 8];
      }
#pragma unroll
      for (int i = 0; i < 2; ++i)
#pragma unroll
        for (int j = 0; j < 4; ++j)
          acc[i][j] = __builtin_amdgcn_mfma_f32_16x16x32_bf16(
              af[i], bfr[j], acc[i][j], 0, 0, 0);
    }
  }
  __syncthreads();   // all waves done with LDS before bounce reuse

  int lr = l >> 3, lc = l & 7;       // blast: 8 lanes per 128B row
  ushort* Tb = &As[0][0] + w * 2048; // wave-private 4 KB bounce

#pragma unroll
  for (int j = 0; j < 4; ++j) {
    float bv = ((flags & 1) && z == 0) ? bias[bn + 16 * j + lm] : 0.f;
#pragma unroll
    for (int i = 0; i < 2; ++i)
#pragma unroll
      for (int r = 0; r < 4; ++r) {
        float v = acc[i][j][r] + bv;
        if (flags & 2) v = fmaxf(v, 0.f);
        Tb[(16 * i + lq * 4 + r) * 64 + 16 * j + lm] = f2bf(v);
      }
  }
  __asm__ __volatile__("" ::: "memory");
#pragma unroll
  for (int p = 0; p < 4; ++p) {
    int rowL = p * 8 + lr;
    bf16x8 vv = *(const bf16x8*)&Tb[rowL * 64 + lc * 8];
    *(bf16x8*)(Cb + (size_t)(bm + w * 32 + rowL) * Nc + bn + lc * 8) = vv;
  }
}

// ---------------- bf16 MFMA GEMM, 64x128 tile (FFN1) ----------------------
// 2 waves, wave-private 64x64 output (8 ds_read_b128 / 16 MFMA), dbuf LDS.
// flags: 1=+bias, 2=relu. bf16 blast output. (R0/R2-validated path.)
__global__ __launch_bounds__(128, 2) void gemm128(
    const ushort* __restrict__ A, const ushort* __restrict__ Bt,
    const float* __restrict__ bias, ushort* __restrict__ Cb,
    int M, int Nc, int Kd, int flags) {
  __shared__ ushort As[2][64 * 64];    // 16 KB
  __shared__ ushort Bs[2][128 * 64];   // 32 KB (buf 0 reused as bounce)
  int tid = threadIdx.x;
  int bm = blockIdx.y * 64, bn = blockIdx.x * 128;
  int T = Kd >> 6;
  int w = tid >> 6, l = tid & 63;
  int lm = l & 15, lq = l >> 4;
  int srow = tid >> 3;
  int sg = tid & 7;

  f32x4 acc[4][4];
#pragma unroll
  for (int i = 0; i < 4; ++i)
#pragma unroll
    for (int j = 0; j < 4; ++j) acc[i][j] = (f32x4){0.f, 0.f, 0.f, 0.f};

  {
#pragma unroll
    for (int r = 0; r < 4; ++r) {
      int row = r * 16 + srow;
      int gl = sg ^ (row & 7);
      async16(&As[0][row * 64 + sg * 8], A + (size_t)(bm + row) * Kd + gl * 8);
    }
#pragma unroll
    for (int r = 0; r < 8; ++r) {
      int row = r * 16 + srow;
      int gl = sg ^ (row & 7);
      async16(&Bs[0][row * 64 + sg * 8], Bt + (size_t)(bn + row) * Kd + gl * 8);
    }
  }
  for (int it = 0; it < T; ++it) {
    int cur = it & 1;
    __syncthreads();
    if (it + 1 < T) {
      int nxt = cur ^ 1;
      int k0 = (it + 1) << 6;
#pragma unroll
      for (int r = 0; r < 4; ++r) {
        int row = r * 16 + srow;
        int gl = sg ^ (row & 7);
        async16(&As[nxt][row * 64 + sg * 8],
                A + (size_t)(bm + row) * Kd + k0 + gl * 8);
      }
#pragma unroll
      for (int r = 0; r < 8; ++r) {
        int row = r * 16 + srow;
        int gl = sg ^ (row & 7);
        async16(&Bs[nxt][row * 64 + sg * 8],
                Bt + (size_t)(bn + row) * Kd + k0 + gl * 8);
      }
    }
#pragma unroll
    for (int kk = 0; kk < 2; ++kk) {
      bf16x8 af[4], bfr[4];
#pragma unroll
      for (int i = 0; i < 4; ++i) {
        int ma = 16 * i + lm;
        af[i] = *(const bf16x8*)&As[cur][ma * 64 + ((kk * 4 + lq) ^ (ma & 7)) * 8];
        int nb = w * 64 + 16 * i + lm;
        bfr[i] = *(const bf16x8*)&Bs[cur][nb * 64 + ((kk * 4 + lq) ^ (nb & 7)) * 8];
      }
#pragma unroll
      for (int i = 0; i < 4; ++i)
#pragma unroll
        for (int j = 0; j < 4; ++j)
          acc[i][j] = __builtin_amdgcn_mfma_f32_16x16x32_bf16(
              af[i], bfr[j], acc[i][j], 0, 0, 0);
    }
  }
  __syncthreads();

  int bcol0 = bn + w * 64;
  int lr = l >> 3, lc = l & 7;
  ushort* Tb = &Bs[0][w * 4096];    // wave-private 64x64 bounce

#pragma unroll
  for (int j = 0; j < 4; ++j) {
    float bv = (flags & 1) ? bias[bcol0 + 16 * j + lm] : 0.f;
#pragma unroll
    for (int i = 0; i < 4; ++i)
#pragma unroll
      for (int r = 0; r < 4; ++r) {
        float v = acc[i][j][r] + bv;
        if (flags & 2) v = fmaxf(v, 0.f);
        Tb[(16 * i + lq * 4 + r) * 64 + 16 * j + lm] = f2bf(v);
      }
  }
  __asm__ __volatile__("" ::: "memory");
#pragma unroll
  for (int p = 0; p < 8; ++p) {
    int rowL = p * 8 + lr;
    bf16x8 vv = *(const bf16x8*)&Tb[rowL * 64 + lc * 8];
    *(bf16x8*)(Cb + (size_t)(bm + rowL) * Nc + bcol0 + lc * 8) = vv;
  }
}

// ---------------- QKV GEMM + (overlapped) wo/w1/w2 transposes -------------
__global__ __launch_bounds__(128, 2) void qkvT(
    const ushort* __restrict__ A, const ushort* __restrict__ Bt,
    ushort* __restrict__ Cb,
    const float* __restrict__ wo, const float* __restrict__ w1,
    const float* __restrict__ w2, ushort* __restrict__ wopT,
    ushort* __restrict__ w1T, ushort* __restrict__ w2T) {
  __shared__ __align__(16) ushort As[2][64 * 64];   // 16 KB (tile overlay)
  __shared__ ushort Bs[2][64 * 64];                 // 16 KB
  int blk = blockIdx.x, tid = threadIdx.x;

  if (blk >= 768) {   // ---- transpose path (128 threads, 32x32 f32 tile)
    float (*tile)[33] = (float(*)[33])&As[0][0];
    int t = blk - 768;
    const float* src; ushort* dst;
    int R, C, Kpad, tX, tIdx;
    if (t < 544)       { tIdx = t;        src = wo; dst = wopT; R = 1032; C = 512;  Kpad = 1088; tX = 16; }
    else if (t < 1568) { tIdx = t - 544;  src = w1; dst = w1T;  R = 512;  C = 2048; Kpad = 512;  tX = 64; }
    else               { tIdx = t - 1568; src = w2; dst = w2T;  R = 2048; C = 512;  Kpad = 2048; tX = 16; }
    int c0 = (tIdx % tX) * 32, r0 = (tIdx / tX) * 32;
    int tx = tid & 7, ty = tid >> 3;   // 8 x 16
#pragma unroll
    for (int yy = 0; yy < 32; yy += 16) {
      int r = r0 + yy + ty, c = c0 + tx * 4;
      float4 v = (r < R) ? *(const float4*)&src[(size_t)r * C + c]
                         : (float4){0.f, 0.f, 0.f, 0.f};
      tile[yy + ty][tx * 4 + 0] = v.x;
      tile[yy + ty][tx * 4 + 1] = v.y;
      tile[yy + ty][tx * 4 + 2] = v.z;
      tile[yy + ty][tx * 4 + 3] = v.w;
    }
    __syncthreads();
#pragma unroll
    for (int yy = 0; yy < 32; yy += 16) {
      int cc = c0 + yy + ty;
      int k = r0 + tx * 4;
      float a0 = tile[tx * 4 + 0][yy + ty];
      float a1 = tile[tx * 4 + 1][yy + ty];
      float a2 = tile[tx * 4 + 2][yy + ty];
      float a3 = tile[tx * 4 + 3][yy + ty];
      ushort pk[4] = {f2bf(a0), f2bf(a1), f2bf(a2), f2bf(a3)};
      *(uint2*)&dst[(size_t)cc * Kpad + k] = *(uint2*)pk;
    }
    return;
  }

  // ---- GEMM path: 64x64 tile, full K=512, head-layout epilogue ----
  int bm = (blk / 24) * 64, bn = (blk % 24) * 64;
  const int Kd = 512, it1 = 8;
  int w = tid >> 6, l = tid & 63;
  int lm = l & 15, lq = l >> 4;
  int srow = tid >> 3;
  int sg = tid & 7;

  f32x4 acc[2][4];
#pragma unroll
  for (int i = 0; i < 2; ++i)
#pragma unroll
    for (int j = 0; j < 4; ++j) acc[i][j] = (f32x4){0.f, 0.f, 0.f, 0.f};

  {
#pragma unroll
    for (int r = 0; r < 4; ++r) {
      int row = r * 16 + srow;
      int gl = sg ^ (row & 7);
      async16(&As[0][row * 64 + sg * 8],
              A + (size_t)(bm + row) * Kd + gl * 8);
      async16(&Bs[0][row * 64 + sg * 8],
              Bt + (size_t)(bn + row) * Kd + gl * 8);
    }
  }
  for (int it = 0; it < it1; ++it) {
    int cur = it & 1;
    __syncthreads();
    if (it + 1 < it1) {
      int nxt = cur ^ 1;
      int k0 = (it + 1) << 6;
#pragma unroll
      for (int r = 0; r < 4; ++r) {
        int row = r * 16 + srow;
        int gl = sg ^ (row & 7);
        async16(&As[nxt][row * 64 + sg * 8],
                A + (size_t)(bm + row) * Kd + k0 + gl * 8);
        async16(&Bs[nxt][row * 64 + sg * 8],
                Bt + (size_t)(bn + row) * Kd + k0 + gl * 8);
      }
    }
#pragma unroll
    for (int kk = 0; kk < 2; ++kk) {
      bf16x8 af[2], bfr[4];
#pragma unroll
      for (int i = 0; i < 2; ++i) {
        int ma = w * 32 + 16 * i + lm;
        af[i] = *(const bf16x8*)&As[cur][ma * 64 + ((kk * 4 + lq) ^ (ma & 7)) * 8];
      }
#pragma unroll
      for (int j = 0; j < 4; ++j) {
        int nb = 16 * j + lm;
        bfr[j] = *(const bf16x8*)&Bs[cur][nb * 64 + ((kk * 4 + lq) ^ (nb & 7)) * 8];
      }
#pragma unroll
      for (int i = 0; i < 2; ++i)
#pragma unroll
        for (int j = 0; j < 4; ++j)
          acc[i][j] = __builtin_amdgcn_mfma_f32_16x16x32_bf16(
              af[i], bfr[j], acc[i][j], 0, 0, 0);
    }
  }
  __syncthreads();

  int lr = l >> 3, lc = l & 7;
  ushort* Tb = &As[0][0] + w * 2048;   // wave-private 4 KB bounce

  int which = bn >> 9;
  int hh = (bn & 511) >> 6;
  int b = bm >> 8, nn0 = bm & 255;
  if (which == 2) {               // v: transpose to [d][n]; wave n = w*32..+31
#pragma unroll
    for (int j = 0; j < 4; ++j)
#pragma unroll
      for (int i = 0; i < 2; ++i) {
        ushort pk[4];
#pragma unroll
        for (int r = 0; r < 4; ++r) pk[r] = f2bf(acc[i][j][r]);
        *(uint2*)&Tb[(16 * j + lm) * 32 + 16 * i + lq * 4] = *(uint2*)pk;
      }
  } else {                        // q,k: [n][d]; wave rows w*32..+31
#pragma unroll
    for (int j = 0; j < 4; ++j)
#pragma unroll
      for (int i = 0; i < 2; ++i)
#pragma unroll
        for (int r = 0; r < 4; ++r)
          Tb[(16 * i + lq * 4 + r) * 64 + 16 * j + lm] = f2bf(acc[i][j][r]);
  }
  __asm__ __volatile__("" ::: "memory");
  ushort* dstb = Cb + (size_t)which * 1048576 + (size_t)(b * 8 + hh) * 16384;
  if (which == 2) {
    int vr = l >> 2, vc = l & 3;  // 16 d-rows x 4 n-chunks per pass
#pragma unroll
    for (int p = 0; p < 4; ++p) {
      int rowL = p * 16 + vr;     // d
      bf16x8 vv = *(const bf16x8*)&Tb[rowL * 32 + vc * 8];
      *(bf16x8*)(dstb + (size_t)rowL * 256 + nn0 + w * 32 + vc * 8) = vv;
    }
  } else {
#pragma unroll
    for (int p = 0; p < 4; ++p) {
      int rowL = p * 8 + lr;      // n-local 0..31
      bf16x8 vv = *(const bf16x8*)&Tb[rowL * 64 + lc * 8];
      *(bf16x8*)(dstb + (size_t)(nn0 + w * 32 + rowL) * 64 + lc * 8) = vv;
    }
  }
}

// ---------------- prep: s->bf16 + wqkv transpose only ---------------------
__global__ __launch_bounds__(256) void prep_small(
    const float* __restrict__ s, __hip_bfloat16* __restrict__ s_bf,
    const float* __restrict__ wq, const float* __restrict__ wk,
    const float* __restrict__ wv, __hip_bfloat16* __restrict__ wqkvT) {
  int blk = blockIdx.x;
  if (blk < 512) {
    int i = blk * 256 + threadIdx.x;   // 131072 threads x 8 elems
    float4 a = ((const float4*)s)[i * 2];
    float4 c = ((const float4*)s)[i * 2 + 1];
    ushort pk[8] = {f2bf(a.x), f2bf(a.y), f2bf(a.z), f2bf(a.w),
                    f2bf(c.x), f2bf(c.y), f2bf(c.z), f2bf(c.w)};
    *(uint4*)&((ushort*)s_bf)[i * 8] = *(uint4*)pk;
    return;
  }
  int t = blk - 512;
  __shared__ float tile[32][33];
  int zz = t >> 8, tIdx = t & 255;
  const float* src = zz == 0 ? wq : zz == 1 ? wk : wv;
  int whichBase = zz * 512;
  int c0 = (tIdx & 15) * 32, r0 = (tIdx >> 4) * 32;
  int tx = threadIdx.x & 7, ty = threadIdx.x >> 3;   // 8 x 32
  {
    int r = r0 + ty, c = c0 + tx * 4;
    float4 v = *(const float4*)&src[(size_t)r * 512 + c];
    tile[ty][tx * 4 + 0] = v.x;
    tile[ty][tx * 4 + 1] = v.y;
    tile[ty][tx * 4 + 2] = v.z;
    tile[ty][tx * 4 + 3] = v.w;
  }
  __syncthreads();
  {
    int cc = c0 + ty;                 // dst row (source col)
    int k = r0 + tx * 4;              // dst col (source row), 4-chunk
    float a0 = tile[tx * 4 + 0][ty];
    float a1 = tile[tx * 4 + 1][ty];
    float a2 = tile[tx * 4 + 2][ty];
    float a3 = tile[tx * 4 + 3][ty];
    int n = whichBase + (cc & 7) * 64 + (cc >> 3);
    ushort pk[4] = {f2bf(a0), f2bf(a1), f2bf(a2), f2bf(a3)};
    *(uint2*)&((ushort*)wqkvT)[(size_t)n * 512 + k] = *(uint2*)pk;
  }
}

// ---------------- fused attention: QK^T+softmax -> a, PV -> o, o_pair -----
__global__ __launch_bounds__(128) void attn_fused(
    const ushort* __restrict__ qh, const ushort* __restrict__ kh,
    const ushort* __restrict__ vT, const int* __restrict__ masks,
    const float* __restrict__ wb, float* __restrict__ a_out,
    ushort* __restrict__ cat) {
  int strip = blockIdx.x & 7, bh = blockIdx.x >> 3;
  int h = bh & 7, b = bh >> 3;
  __shared__ ushort Ks[256 * 64];   // 32 KB
  __shared__ ushort Ps[32 * 64];    // 4 KB, k-quarter P (wave-private rows)
  __shared__ float wbs[NB_];
  __shared__ float mfj[256];
  int tid = threadIdx.x;
  int srow = tid >> 3, sg = tid & 7;
#pragma unroll
  for (int rr = 0; rr < 16; ++rr) {
    int row = rr * 16 + srow;
    int gl = sg ^ (row & 7);
    async16(&Ks[row * 64 + sg * 8],
            kh + ((size_t)bh * 256 + row) * 64 + gl * 8);
  }
  int w = tid >> 6, l = tid & 63, lm = l & 15, lq = l >> 4;
  bf16x8 qf[2];
  {
    const ushort* qrow =
        qh + ((size_t)bh * 256 + strip * 32 + w * 16 + lm) * 64 + lq * 8;
    qf[0] = *(const bf16x8*)qrow;
    qf[1] = *(const bf16x8*)(qrow + 32);
  }
  if (tid < NB_) wbs[tid] = wb[tid * H_ + h];
  mfj[tid]       = (masks[b * 256 + tid] != 0) ? 1.f : 0.f;
  mfj[tid + 128] = (masks[b * 256 + tid + 128] != 0) ? 1.f : 0.f;
  __syncthreads();   // the only barrier

  f32x4 acc[16];
#pragma unroll
  for (int ct = 0; ct < 16; ++ct) {
    int krow = ct * 16 + lm;
    bf16x8 kf0 = *(const bf16x8*)&Ks[krow * 64 + ((lq) ^ (krow & 7)) * 8];
    bf16x8 kf1 = *(const bf16x8*)&Ks[krow * 64 + ((4 + lq) ^ (krow & 7)) * 8];
    f32x4 zf = (f32x4){0.f, 0.f, 0.f, 0.f};
    zf = __builtin_amdgcn_mfma_f32_16x16x32_bf16(qf[0], kf0, zf, 0, 0, 0);
    acc[ct] = __builtin_amdgcn_mfma_f32_16x16x32_bf16(qf[1], kf1, zf, 0, 0, 0);
  }
  int ibase = strip * 32 + w * 16 + lq * 4;
  float mfi[4];
#pragma unroll
  for (int r = 0; r < 4; ++r) mfi[r] = mfj[ibase + r];
#pragma unroll
  for (int ct = 0; ct < 16; ++ct) {
    int j = ct * 16 + lm;
    float mj = mfj[j];
#pragma unroll
    for (int r = 0; r < 4; ++r) {
      int i = ibase + r;
      int diff = i - j;
      int cb = diff < -K_ ? 0 : (diff > K_ ? 2 * K_ : diff + K_);
      float sq = mfi[r] * mj;
      acc[ct][r] = WL_ * (acc[ct][r] * 0.125f + wbs[cb] * sq) - 1e9f * (1.f - sq);
    }
  }
  float mx[4], sm[4];
#pragma unroll
  for (int r = 0; r < 4; ++r) {
    float m = acc[0][r];
#pragma unroll
    for (int ct = 1; ct < 16; ++ct) m = fmaxf(m, acc[ct][r]);
#pragma unroll
    for (int o = 1; o < 16; o <<= 1) m = fmaxf(m, __shfl_xor(m, o, 64));
    mx[r] = m;
  }
#pragma unroll
  for (int ct = 0; ct < 16; ++ct)
#pragma unroll
    for (int r = 0; r < 4; ++r) acc[ct][r] = __expf(acc[ct][r] - mx[r]);
#pragma unroll
  for (int r = 0; r < 4; ++r) {
    float s = 0.f;
#pragma unroll
    for (int ct = 0; ct < 16; ++ct) s += acc[ct][r];
#pragma unroll
    for (int o = 1; o < 16; o <<= 1) s += __shfl_xor(s, o, 64);
    sm[r] = 1.f / s;
  }
  // ---- a stores (f32) + o_pair into cat (bf16) ----
  float p0[4] = {0.f, 0.f, 0.f, 0.f}, p64[4] = {0.f, 0.f, 0.f, 0.f};
#pragma unroll
  for (int ct = 0; ct < 16; ++ct) {
    int j = ct * 16 + lm;
    float mj = mfj[j];
#pragma unroll
    for (int r = 0; r < 4; ++r) {
      int i = ibase + r;
      float aval = acc[ct][r] * sm[r];
      a_out[((size_t)bh * 256 + i) * 256 + j] = aval;
      float val = aval * mfi[r] * mj;
      int diff = i - j;
      if (diff <= -K_)      p0[r] += val;
      else if (diff >= K_)  p64[r] += val;
      else cat[((size_t)(b * 256 + i)) * 1088 + h * 65 + diff + K_] = f2bf(val);
    }
  }
#pragma unroll
  for (int r = 0; r < 4; ++r)
#pragma unroll
    for (int o = 1; o < 16; o <<= 1) {
      p0[r]  += __shfl_xor(p0[r], o, 64);
      p64[r] += __shfl_xor(p64[r], o, 64);
    }
  if (lm == 0) {
#pragma unroll
    for (int r = 0; r < 4; ++r) {
      int i = ibase + r;
      cat[((size_t)(b * 256 + i)) * 1088 + h * 65 + 0]      = f2bf(p0[r]);
      cat[((size_t)(b * 256 + i)) * 1088 + h * 65 + 2 * K_] = f2bf(p64[r]);
    }
  }
  // interior bins with out-of-range source j -> 0
#pragma unroll
  for (int r = 0; r < 4; ++r) {
    int i = ibase + r;
#pragma unroll
    for (int t = 0; t < 4; ++t) {
      int c = 1 + lm + 16 * t;
      if (c < 64) {
        int j = i - c + K_;
        if (j < 0 || j > 255)
          cat[((size_t)(b * 256 + i)) * 1088 + h * 65 + c] = 0;
      }
    }
  }
  // pad cols 1032..1088 zeroed by h==0 blocks
  if (h == 0) {
    for (int idx = tid; idx < 32 * 56; idx += 128) {
      int r = idx / 56, c = 1032 + (idx - r * 56);
      cat[((size_t)(b * 256 + strip * 32 + r)) * 1088 + c] = 0;
    }
  }
  // ---- PV: o = P @ V over 4 k-quarters; V frags direct from global ----
  f32x4 acc2[4];
#pragma unroll
  for (int nt = 0; nt < 4; ++nt) acc2[nt] = (f32x4){0.f, 0.f, 0.f, 0.f};
  const ushort* vbase = vT + (size_t)bh * 16384;
#pragma unroll
  for (int qt = 0; qt < 4; ++qt) {
    bf16x8 vf0[4], vf1[4];
#pragma unroll
    for (int nt = 0; nt < 4; ++nt) {
      const ushort* vrow = vbase + (size_t)(nt * 16 + lm) * 256 + qt * 64 + lq * 8;
      vf0[nt] = *(const bf16x8*)vrow;
      vf1[nt] = *(const bf16x8*)(vrow + 32);
    }
#pragma unroll
    for (int ctl = 0; ctl < 4; ++ctl) {
      int ct = qt * 4 + ctl;
#pragma unroll
      for (int r = 0; r < 4; ++r) {
        int rowl = w * 16 + lq * 4 + r;
        int g = ctl * 2 + (lm >> 3);
        Ps[rowl * 64 + ((g ^ (rowl & 7)) << 3) + (lm & 7)] =
            f2bf(acc[ct][r] * sm[r]);
      }
    }
    int prow = w * 16 + lm;
#pragma unroll
    for (int kst = 0; kst < 2; ++kst) {
      bf16x8 af = *(const bf16x8*)&Ps[prow * 64 + (((kst * 4 + lq) ^ (prow & 7)) << 3)];
#pragma unroll
      for (int nt = 0; nt < 4; ++nt)
        acc2[nt] = __builtin_amdgcn_mfma_f32_16x16x32_bf16(
            af, kst ? vf1[nt] : vf0[nt], acc2[nt], 0, 0, 0);
    }
  }
#pragma unroll
  for (int nt = 0; nt < 4; ++nt) {
    int d = nt * 16 + lm;
#pragma unroll
    for (int r = 0; r < 4; ++r) {
      int i = ibase + r;
      cat[((size_t)(b * 256 + i)) * 1088 + 520 + h * 64 + d] = f2bf(acc2[nt][r]);
    }
  }
}

// ---------------- out = LayerNorm(x1 + sum_s xp_bf16[s]) * g + b ----------
// 512 blocks x 4 rows each (row-loop; red reused with trailing barrier).
__global__ __launch_bounds__(128) void ln_sum(
    const float* __restrict__ x1, const ushort* __restrict__ xp,
    int S, int stride, const float* __restrict__ g,
    const float* __restrict__ bta, float* __restrict__ out,
    __hip_bfloat16* __restrict__ out_bf) {
  __shared__ float redA[2], redB[2];
  int tid = threadIdx.x;
  int w = tid >> 6;
  float4 gv = *(const float4*)(g + tid * 4);
  float4 bv = *(const float4*)(bta + tid * 4);
#pragma unroll
  for (int rr = 0; rr < 4; ++rr) {
    int row = blockIdx.x + rr * 512;
    size_t base = (size_t)row * 512;
    float4 v = *(const float4*)(x1 + base + tid * 4);
    for (int s = 0; s < S; ++s) {
      uint2 p = *(const uint2*)(xp + (size_t)s * stride + base + tid * 4);
      v.x += bf2f((ushort)(p.x & 0xffff));
      v.y += bf2f((ushort)(p.x >> 16));
      v.z += bf2f((ushort)(p.y & 0xffff));
      v.w += bf2f((ushort)(p.y >> 16));
    }
    float su = v.x + v.y + v.z + v.w;
    float sq = v.x * v.x + v.y * v.y + v.z * v.z + v.w * v.w;
#pragma unroll
    for (int o = 32; o > 0; o >>= 1) {
      su += __shfl_xor(su, o, 64);
      sq += __shfl_xor(sq, o, 64);
    }
    if ((tid & 63) == 0) { redA[w] = su; redB[w] = sq; }
    __syncthreads();
    su = redA[0] + redA[1]; sq = redB[0] + redB[1];
    float mean = su * (1.f / 512.f);
    float var = sq * (1.f / 512.f) - mean * mean;
    float inv = rsqrtf(var + 1e-5f);
    float4 o4;
    o4.x = (v.x - mean) * inv * gv.x + bv.x;
    o4.y = (v.y - mean) * inv * gv.y + bv.y;
    o4.z = (v.z - mean) * inv * gv.z + bv.z;
    o4.w = (v.w - mean) * inv * gv.w + bv.w;
    *(float4*)(out + base + tid * 4) = o4;
    if (out_bf) {
      ushort pk[4] = {f2bf(o4.x), f2bf(o4.y), f2bf(o4.z), f2bf(o4.w)};
      *(uint2*)&((ushort*)out_bf)[base + tid * 4] = *(uint2*)pk;
    }
    __syncthreads();   // red reused next row
  }
}

extern "C" void kernel_launch(void* const* d_in, const int* in_sizes, int n_in,
                              void* d_out, int out_size, void* d_ws, size_t ws_size,
                              hipStream_t stream) {
  const float* s     = (const float*)d_in[0];
  const int*   masks = (const int*)d_in[1];
  const float* wq = (const float*)d_in[2];
  const float* wk = (const float*)d_in[3];
  const float* wv = (const float*)d_in[4];
  const float* wb = (const float*)d_in[5];
  const float* wo = (const float*)d_in[6];
  const float* bo = (const float*)d_in[7];
  const float* ln1_g = (const float*)d_in[8];
  const float* ln1_b = (const float*)d_in[9];
  const float* w1 = (const float*)d_in[10];
  const float* b1 = (const float*)d_in[11];
  const float* w2 = (const float*)d_in[12];
  const float* b2 = (const float*)d_in[13];
  const float* ln2_g = (const float*)d_in[14];
  const float* ln2_b = (const float*)d_in[15];

  float* out_x = (float*)d_out;              // [8,256,512]
  float* out_a = out_x + 1048576;            // [8,8,256,256]

  // disjoint workspace (float offsets)
  float* ws = (float*)d_ws;
  ushort* embd_part = (ushort*)(ws + 0);                   // [2][2048,512] bf16
  float* xbuf       = ws + 4194304;
  ushort* ff_part   = (ushort*)(ws + 5242880);             // [2][2048,512] bf16
  ushort* qkv_bf    = (ushort*)(ws + 9437184);             // q|k [B,H,N,D], v [B,H,D,N]
  ushort* q_bf = qkv_bf;
  ushort* k_bf = qkv_bf + 1048576;
  ushort* v_bf = qkv_bf + 2097152;
  ushort* cat_bf = (ushort*)(ws + 10223616);               // [2048,1088]
  __hip_bfloat16* h_bf  = (__hip_bfloat16*)(ws + 11337728);  // [2048,2048]
  __hip_bfloat16* s_bf  = (__hip_bfloat16*)(ws + 13434880);  // [2048,512]
  __hip_bfloat16* x_bf  = (__hip_bfloat16*)(ws + 13959168);  // [2048,512]
  __hip_bfloat16* wqkvT = (__hip_bfloat16*)(ws + 14483456);  // [1536,512]
  ushort* wopT  = (ushort*)(ws + 14876672);                // [512,1088]
  ushort* w1T   = (ushort*)(ws + 15155200);                // [2048,512]
  ushort* w2T   = (ushort*)(ws + 15679488);                // [512,2048]

  dim3 blkg(128);
  // 0. prep: s cvt (512 blocks) + wqkv transpose (768 blocks)
  prep_small<<<dim3(1280), dim3(256), 0, stream>>>(s, s_bf, wq, wk, wv, wqkvT);
  // 1. QKV projection (768 gemm blocks) + wo/w1/w2 transposes (2592 blocks)
  qkvT<<<dim3(3360), blkg, 0, stream>>>(
      (const ushort*)s_bf, (const ushort*)wqkvT, qkv_bf,
      wo, w1, w2, wopT, w1T, w2T);
  // 2. fused attention: a -> d_out, o + o_pair -> cat_bf  [512 x 128thr]
  attn_fused<<<dim3(512), blkg, 0, stream>>>(q_bf, k_bf, v_bf, masks, wb,
                                             out_a, cat_bf);
  // 3. output projection (split-K=2, bf16 partials)  [512 blocks]
  gemm_bf16<<<dim3(8, 32, 2), blkg, 0, stream>>>(
      cat_bf, wopT, bo, nullptr, embd_part, 2048, 512, 1088, 1 | 32);
  // 4. x = LN(s + sum embd_part)  [512 blocks x 4 rows]
  ln_sum<<<dim3(512), blkg, 0, stream>>>(s, embd_part, 2, 1048576,
                                         ln1_g, ln1_b, xbuf, x_bf);
  // 5. FFN1: 64x128 tiles  [512 blocks]
  gemm128<<<dim3(16, 32, 1), blkg, 0, stream>>>(
      (const ushort*)x_bf, w1T, b1, (ushort*)h_bf, 2048, 2048, 512, 1 | 2);
  // 6. FFN2 (split-K=2)  [512 blocks]
  gemm_bf16<<<dim3(8, 32, 2), blkg, 0, stream>>>(
      (const ushort*)h_bf, w2T, b2, nullptr, ff_part,
      2048, 512, 2048, 1 | 32);
  // 7. out = LN(x + sum ff_part)  [512 blocks x 4 rows]
  ln_sum<<<dim3(512), blkg, 0, stream>>>(xbuf, ff_part, 2, 1048576,
                                         ln2_g, ln2_b, out_x, nullptr);
}

// Round 9
// 169.214 us; speedup vs baseline: 1.1376x; 1.0340x over previous
//
#include <hip/hip_runtime.h>
#include <hip/hip_bf16.h>
#include <cstdint>

#define B_ 8
#define N_ 256
#define CS_ 512
#define H_ 8
#define D_ 64
#define K_ 32
#define NB_ 65
#define CT_ 2048
#define WL_ 0.70710678118654752f

typedef __attribute__((ext_vector_type(8))) short bf16x8;
typedef __attribute__((ext_vector_type(4))) float f32x4;

#define GLOBAL_AS __attribute__((address_space(1)))
#define LDS_AS __attribute__((address_space(3)))

__device__ __forceinline__ void async16(void* lds, const void* g) {
  __builtin_amdgcn_global_load_lds((const GLOBAL_AS uint32_t*)g,
                                   (LDS_AS uint32_t*)lds, 16, 0, 0);
}

__device__ __forceinline__ ushort f2bf(float v) {
  __hip_bfloat16 hb = __float2bfloat16(v);
  return *(ushort*)&hb;
}

__device__ __forceinline__ float bf2f(ushort u) {
  union { uint32_t ui; float f; } cv; cv.ui = (uint32_t)u << 16;
  return cv.f;
}

// ---------------- bf16 MFMA GEMM: C[M,N] = A[M,K] @ Bt[N,K]^T -------------
// 64x64 tile, 128 threads (2 waves, wave = 32 rows x 64 cols), dbuf LDS.
// flags: 1=+bias[col] (slice 0), 2=relu, 4=bf16 out via LDS-coalesced blast,
//        32=offset bf16 out by z*M*Nc (bf16 split-K partials).
__global__ __launch_bounds__(128, 2) void gemm_bf16(
    const ushort* __restrict__ A, const ushort* __restrict__ Bt,
    const float* __restrict__ bias, float* __restrict__ C,
    ushort* __restrict__ Cb, int M, int Nc, int Kd, int flags) {
  __shared__ ushort As[2][64 * 64];   // 16 KB (buf reused as epilogue bounce)
  __shared__ ushort Bs[2][64 * 64];   // 16 KB
  int tid = threadIdx.x;
  int bm = blockIdx.y * 64, bn = blockIdx.x * 64;
  int S = gridDim.z, z = blockIdx.z;
  int T = Kd >> 6;
  int it0 = (z * T) / S, it1 = ((z + 1) * T) / S;
  if (flags & 32) Cb += (size_t)z * M * Nc;
  int w = tid >> 6, l = tid & 63;
  int lm = l & 15, lq = l >> 4;
  int srow = tid >> 3;       // 0..15
  int sg = tid & 7;

  f32x4 acc[2][4];
#pragma unroll
  for (int i = 0; i < 2; ++i)
#pragma unroll
    for (int j = 0; j < 4; ++j) acc[i][j] = (f32x4){0.f, 0.f, 0.f, 0.f};

  // prologue: issue loads for first tile into buf 0 (8 x async16 = 16 KB)
  {
    int k0 = it0 << 6;
#pragma unroll
    for (int r = 0; r < 4; ++r) {
      int row = r * 16 + srow;
      int gl = sg ^ (row & 7);
      async16(&As[0][row * 64 + sg * 8],
              A + (size_t)(bm + row) * Kd + k0 + gl * 8);
      async16(&Bs[0][row * 64 + sg * 8],
              Bt + (size_t)(bn + row) * Kd + k0 + gl * 8);
    }
  }
  for (int it = it0; it < it1; ++it) {
    int cur = (it - it0) & 1;
    __syncthreads();   // cur tile's loads complete; nxt buf's readers done
    if (it + 1 < it1) {
      int nxt = cur ^ 1;
      int k0 = (it + 1) << 6;
#pragma unroll
      for (int r = 0; r < 4; ++r) {
        int row = r * 16 + srow;
        int gl = sg ^ (row & 7);
        async16(&As[nxt][row * 64 + sg * 8],
                A + (size_t)(bm + row) * Kd + k0 + gl * 8);
        async16(&Bs[nxt][row * 64 + sg * 8],
                Bt + (size_t)(bn + row) * Kd + k0 + gl * 8);
      }
    }
#pragma unroll
    for (int kk = 0; kk < 2; ++kk) {
      bf16x8 af[2], bfr[4];
#pragma unroll
      for (int i = 0; i < 2; ++i) {
        int ma = w * 32 + 16 * i + lm;
        af[i] = *(const bf16x8*)&As[cur][ma * 64 + ((kk * 4 + lq) ^ (ma & 7)) * 8];
      }
#pragma unroll
      for (int j = 0; j < 4; ++j) {
        int nb = 16 * j + lm;
        bfr[j] = *(const bf16x8*)&Bs[cur][nb * 64 + ((kk * 4 + lq) ^ (nb & 7)) * 8];
      }
#pragma unroll
      for (int i = 0; i < 2; ++i)
#pragma unroll
        for (int j = 0; j < 4; ++j)
          acc[i][j] = __builtin_amdgcn_mfma_f32_16x16x32_bf16(
              af[i], bfr[j], acc[i][j], 0, 0, 0);
    }
  }
  __syncthreads();   // all waves done with LDS before bounce reuse

  int lr = l >> 3, lc = l & 7;       // blast: 8 lanes per 128B row
  ushort* Tb = &As[0][0] + w * 2048; // wave-private 4 KB bounce

  // bf16 output: coalesced blast (flags & 4)
#pragma unroll
  for (int j = 0; j < 4; ++j) {
    float bv = ((flags & 1) && z == 0) ? bias[bn + 16 * j + lm] : 0.f;
#pragma unroll
    for (int i = 0; i < 2; ++i)
#pragma unroll
      for (int r = 0; r < 4; ++r) {
        float v = acc[i][j][r] + bv;
        if (flags & 2) v = fmaxf(v, 0.f);
        Tb[(16 * i + lq * 4 + r) * 64 + 16 * j + lm] = f2bf(v);
      }
  }
  __asm__ __volatile__("" ::: "memory");
#pragma unroll
  for (int p = 0; p < 4; ++p) {
    int rowL = p * 8 + lr;
    bf16x8 vv = *(const bf16x8*)&Tb[rowL * 64 + lc * 8];
    *(bf16x8*)(Cb + (size_t)(bm + w * 32 + rowL) * Nc + bn + lc * 8) = vv;
  }
}

// ---------------- QKV GEMM + (overlapped) wo/w1/w2 transposes -------------
// blk < 768: 64x64 GEMM tile into head-layout epilogue (validated R1 path).
// blk >= 768: one 32x32 transpose tile of wo/w1/w2 (validated R4 path) —
// rides in QKV's latency bubbles; outputs needed only 2+ kernels later.
__global__ __launch_bounds__(128, 2) void qkvT(
    const ushort* __restrict__ A, const ushort* __restrict__ Bt,
    ushort* __restrict__ Cb,
    const float* __restrict__ wo, const float* __restrict__ w1,
    const float* __restrict__ w2, ushort* __restrict__ wopT,
    ushort* __restrict__ w1T, ushort* __restrict__ w2T) {
  __shared__ __align__(16) ushort As[2][64 * 64];   // 16 KB (tile overlay)
  __shared__ ushort Bs[2][64 * 64];                 // 16 KB
  int blk = blockIdx.x, tid = threadIdx.x;

  if (blk >= 768) {   // ---- transpose path (128 threads, 32x32 f32 tile)
    float (*tile)[33] = (float(*)[33])&As[0][0];
    int t = blk - 768;
    const float* src; ushort* dst;
    int R, C, Kpad, tX, tIdx;
    if (t < 544)       { tIdx = t;        src = wo; dst = wopT; R = 1032; C = 512;  Kpad = 1088; tX = 16; }
    else if (t < 1568) { tIdx = t - 544;  src = w1; dst = w1T;  R = 512;  C = 2048; Kpad = 512;  tX = 64; }
    else               { tIdx = t - 1568; src = w2; dst = w2T;  R = 2048; C = 512;  Kpad = 2048; tX = 16; }
    int c0 = (tIdx % tX) * 32, r0 = (tIdx / tX) * 32;
    int tx = tid & 7, ty = tid >> 3;   // 8 x 16
#pragma unroll
    for (int yy = 0; yy < 32; yy += 16) {
      int r = r0 + yy + ty, c = c0 + tx * 4;
      float4 v = (r < R) ? *(const float4*)&src[(size_t)r * C + c]
                         : (float4){0.f, 0.f, 0.f, 0.f};
      tile[yy + ty][tx * 4 + 0] = v.x;
      tile[yy + ty][tx * 4 + 1] = v.y;
      tile[yy + ty][tx * 4 + 2] = v.z;
      tile[yy + ty][tx * 4 + 3] = v.w;
    }
    __syncthreads();
#pragma unroll
    for (int yy = 0; yy < 32; yy += 16) {
      int cc = c0 + yy + ty;
      int k = r0 + tx * 4;
      float a0 = tile[tx * 4 + 0][yy + ty];
      float a1 = tile[tx * 4 + 1][yy + ty];
      float a2 = tile[tx * 4 + 2][yy + ty];
      float a3 = tile[tx * 4 + 3][yy + ty];
      ushort pk[4] = {f2bf(a0), f2bf(a1), f2bf(a2), f2bf(a3)};
      *(uint2*)&dst[(size_t)cc * Kpad + k] = *(uint2*)pk;
    }
    return;
  }

  // ---- GEMM path: 64x64 tile, full K=512, head-layout epilogue ----
  int bm = (blk / 24) * 64, bn = (blk % 24) * 64;
  const int Kd = 512, it1 = 8;
  int w = tid >> 6, l = tid & 63;
  int lm = l & 15, lq = l >> 4;
  int srow = tid >> 3;
  int sg = tid & 7;

  f32x4 acc[2][4];
#pragma unroll
  for (int i = 0; i < 2; ++i)
#pragma unroll
    for (int j = 0; j < 4; ++j) acc[i][j] = (f32x4){0.f, 0.f, 0.f, 0.f};

  {
#pragma unroll
    for (int r = 0; r < 4; ++r) {
      int row = r * 16 + srow;
      int gl = sg ^ (row & 7);
      async16(&As[0][row * 64 + sg * 8],
              A + (size_t)(bm + row) * Kd + gl * 8);
      async16(&Bs[0][row * 64 + sg * 8],
              Bt + (size_t)(bn + row) * Kd + gl * 8);
    }
  }
  for (int it = 0; it < it1; ++it) {
    int cur = it & 1;
    __syncthreads();
    if (it + 1 < it1) {
      int nxt = cur ^ 1;
      int k0 = (it + 1) << 6;
#pragma unroll
      for (int r = 0; r < 4; ++r) {
        int row = r * 16 + srow;
        int gl = sg ^ (row & 7);
        async16(&As[nxt][row * 64 + sg * 8],
                A + (size_t)(bm + row) * Kd + k0 + gl * 8);
        async16(&Bs[nxt][row * 64 + sg * 8],
                Bt + (size_t)(bn + row) * Kd + k0 + gl * 8);
      }
    }
#pragma unroll
    for (int kk = 0; kk < 2; ++kk) {
      bf16x8 af[2], bfr[4];
#pragma unroll
      for (int i = 0; i < 2; ++i) {
        int ma = w * 32 + 16 * i + lm;
        af[i] = *(const bf16x8*)&As[cur][ma * 64 + ((kk * 4 + lq) ^ (ma & 7)) * 8];
      }
#pragma unroll
      for (int j = 0; j < 4; ++j) {
        int nb = 16 * j + lm;
        bfr[j] = *(const bf16x8*)&Bs[cur][nb * 64 + ((kk * 4 + lq) ^ (nb & 7)) * 8];
      }
#pragma unroll
      for (int i = 0; i < 2; ++i)
#pragma unroll
        for (int j = 0; j < 4; ++j)
          acc[i][j] = __builtin_amdgcn_mfma_f32_16x16x32_bf16(
              af[i], bfr[j], acc[i][j], 0, 0, 0);
    }
  }
  __syncthreads();

  int lr = l >> 3, lc = l & 7;
  ushort* Tb = &As[0][0] + w * 2048;   // wave-private 4 KB bounce

  int which = bn >> 9;
  int hh = (bn & 511) >> 6;
  int b = bm >> 8, nn0 = bm & 255;
  if (which == 2) {               // v: transpose to [d][n]; wave n = w*32..+31
#pragma unroll
    for (int j = 0; j < 4; ++j)
#pragma unroll
      for (int i = 0; i < 2; ++i) {
        ushort pk[4];
#pragma unroll
        for (int r = 0; r < 4; ++r) pk[r] = f2bf(acc[i][j][r]);
        *(uint2*)&Tb[(16 * j + lm) * 32 + 16 * i + lq * 4] = *(uint2*)pk;
      }
  } else {                        // q,k: [n][d]; wave rows w*32..+31
#pragma unroll
    for (int j = 0; j < 4; ++j)
#pragma unroll
      for (int i = 0; i < 2; ++i)
#pragma unroll
        for (int r = 0; r < 4; ++r)
          Tb[(16 * i + lq * 4 + r) * 64 + 16 * j + lm] = f2bf(acc[i][j][r]);
  }
  __asm__ __volatile__("" ::: "memory");
  ushort* dstb = Cb + (size_t)which * 1048576 + (size_t)(b * 8 + hh) * 16384;
  if (which == 2) {
    int vr = l >> 2, vc = l & 3;  // 16 d-rows x 4 n-chunks per pass
#pragma unroll
    for (int p = 0; p < 4; ++p) {
      int rowL = p * 16 + vr;     // d
      bf16x8 vv = *(const bf16x8*)&Tb[rowL * 32 + vc * 8];
      *(bf16x8*)(dstb + (size_t)rowL * 256 + nn0 + w * 32 + vc * 8) = vv;
    }
  } else {
#pragma unroll
    for (int p = 0; p < 4; ++p) {
      int rowL = p * 8 + lr;      // n-local 0..31
      bf16x8 vv = *(const bf16x8*)&Tb[rowL * 64 + lc * 8];
      *(bf16x8*)(dstb + (size_t)(nn0 + w * 32 + rowL) * 64 + lc * 8) = vv;
    }
  }
}

// ---------------- prep: s->bf16 + wqkv transpose only ---------------------
__global__ __launch_bounds__(256) void prep_small(
    const float* __restrict__ s, __hip_bfloat16* __restrict__ s_bf,
    const float* __restrict__ wq, const float* __restrict__ wk,
    const float* __restrict__ wv, __hip_bfloat16* __restrict__ wqkvT) {
  int blk = blockIdx.x;
  if (blk < 512) {
    int i = blk * 256 + threadIdx.x;   // 131072 threads x 8 elems
    float4 a = ((const float4*)s)[i * 2];
    float4 c = ((const float4*)s)[i * 2 + 1];
    ushort pk[8] = {f2bf(a.x), f2bf(a.y), f2bf(a.z), f2bf(a.w),
                    f2bf(c.x), f2bf(c.y), f2bf(c.z), f2bf(c.w)};
    *(uint4*)&((ushort*)s_bf)[i * 8] = *(uint4*)pk;
    return;
  }
  int t = blk - 512;
  __shared__ float tile[32][33];
  int zz = t >> 8, tIdx = t & 255;
  const float* src = zz == 0 ? wq : zz == 1 ? wk : wv;
  int whichBase = zz * 512;
  int c0 = (tIdx & 15) * 32, r0 = (tIdx >> 4) * 32;
  int tx = threadIdx.x & 7, ty = threadIdx.x >> 3;   // 8 x 32
  {
    int r = r0 + ty, c = c0 + tx * 4;
    float4 v = *(const float4*)&src[(size_t)r * 512 + c];
    tile[ty][tx * 4 + 0] = v.x;
    tile[ty][tx * 4 + 1] = v.y;
    tile[ty][tx * 4 + 2] = v.z;
    tile[ty][tx * 4 + 3] = v.w;
  }
  __syncthreads();
  {
    int cc = c0 + ty;                 // dst row (source col)
    int k = r0 + tx * 4;              // dst col (source row), 4-chunk
    float a0 = tile[tx * 4 + 0][ty];
    float a1 = tile[tx * 4 + 1][ty];
    float a2 = tile[tx * 4 + 2][ty];
    float a3 = tile[tx * 4 + 3][ty];
    int n = whichBase + (cc & 7) * 64 + (cc >> 3);
    ushort pk[4] = {f2bf(a0), f2bf(a1), f2bf(a2), f2bf(a3)};
    *(uint2*)&((ushort*)wqkvT)[(size_t)n * 512 + k] = *(uint2*)pk;
  }
}

// ---------------- fused attention: QK^T+softmax -> a, PV -> o, o_pair -----
__global__ __launch_bounds__(128) void attn_fused(
    const ushort* __restrict__ qh, const ushort* __restrict__ kh,
    const ushort* __restrict__ vT, const int* __restrict__ masks,
    const float* __restrict__ wb, float* __restrict__ a_out,
    ushort* __restrict__ cat) {
  int strip = blockIdx.x & 7, bh = blockIdx.x >> 3;
  int h = bh & 7, b = bh >> 3;
  __shared__ ushort Ks[256 * 64];   // 32 KB
  __shared__ ushort Ps[32 * 64];    // 4 KB, k-quarter P (wave-private rows)
  __shared__ float wbs[NB_];
  __shared__ float mfj[256];
  int tid = threadIdx.x;
  int srow = tid >> 3, sg = tid & 7;
#pragma unroll
  for (int rr = 0; rr < 16; ++rr) {
    int row = rr * 16 + srow;
    int gl = sg ^ (row & 7);
    async16(&Ks[row * 64 + sg * 8],
            kh + ((size_t)bh * 256 + row) * 64 + gl * 8);
  }
  int w = tid >> 6, l = tid & 63, lm = l & 15, lq = l >> 4;
  bf16x8 qf[2];
  {
    const ushort* qrow =
        qh + ((size_t)bh * 256 + strip * 32 + w * 16 + lm) * 64 + lq * 8;
    qf[0] = *(const bf16x8*)qrow;
    qf[1] = *(const bf16x8*)(qrow + 32);
  }
  if (tid < NB_) wbs[tid] = wb[tid * H_ + h];
  mfj[tid]       = (masks[b * 256 + tid] != 0) ? 1.f : 0.f;
  mfj[tid + 128] = (masks[b * 256 + tid + 128] != 0) ? 1.f : 0.f;
  __syncthreads();   // the only barrier

  f32x4 acc[16];
#pragma unroll
  for (int ct = 0; ct < 16; ++ct) {
    int krow = ct * 16 + lm;
    bf16x8 kf0 = *(const bf16x8*)&Ks[krow * 64 + ((lq) ^ (krow & 7)) * 8];
    bf16x8 kf1 = *(const bf16x8*)&Ks[krow * 64 + ((4 + lq) ^ (krow & 7)) * 8];
    f32x4 zf = (f32x4){0.f, 0.f, 0.f, 0.f};
    zf = __builtin_amdgcn_mfma_f32_16x16x32_bf16(qf[0], kf0, zf, 0, 0, 0);
    acc[ct] = __builtin_amdgcn_mfma_f32_16x16x32_bf16(qf[1], kf1, zf, 0, 0, 0);
  }
  int ibase = strip * 32 + w * 16 + lq * 4;
  float mfi[4];
#pragma unroll
  for (int r = 0; r < 4; ++r) mfi[r] = mfj[ibase + r];
#pragma unroll
  for (int ct = 0; ct < 16; ++ct) {
    int j = ct * 16 + lm;
    float mj = mfj[j];
#pragma unroll
    for (int r = 0; r < 4; ++r) {
      int i = ibase + r;
      int diff = i - j;
      int cb = diff < -K_ ? 0 : (diff > K_ ? 2 * K_ : diff + K_);
      float sq = mfi[r] * mj;
      acc[ct][r] = WL_ * (acc[ct][r] * 0.125f + wbs[cb] * sq) - 1e9f * (1.f - sq);
    }
  }
  float mx[4], sm[4];
#pragma unroll
  for (int r = 0; r < 4; ++r) {
    float m = acc[0][r];
#pragma unroll
    for (int ct = 1; ct < 16; ++ct) m = fmaxf(m, acc[ct][r]);
#pragma unroll
    for (int o = 1; o < 16; o <<= 1) m = fmaxf(m, __shfl_xor(m, o, 64));
    mx[r] = m;
  }
#pragma unroll
  for (int ct = 0; ct < 16; ++ct)
#pragma unroll
    for (int r = 0; r < 4; ++r) acc[ct][r] = __expf(acc[ct][r] - mx[r]);
#pragma unroll
  for (int r = 0; r < 4; ++r) {
    float s = 0.f;
#pragma unroll
    for (int ct = 0; ct < 16; ++ct) s += acc[ct][r];
#pragma unroll
    for (int o = 1; o < 16; o <<= 1) s += __shfl_xor(s, o, 64);
    sm[r] = 1.f / s;
  }
  // ---- a stores (f32) + o_pair into cat (bf16) ----
  float p0[4] = {0.f, 0.f, 0.f, 0.f}, p64[4] = {0.f, 0.f, 0.f, 0.f};
#pragma unroll
  for (int ct = 0; ct < 16; ++ct) {
    int j = ct * 16 + lm;
    float mj = mfj[j];
#pragma unroll
    for (int r = 0; r < 4; ++r) {
      int i = ibase + r;
      float aval = acc[ct][r] * sm[r];
      a_out[((size_t)bh * 256 + i) * 256 + j] = aval;
      float val = aval * mfi[r] * mj;
      int diff = i - j;
      if (diff <= -K_)      p0[r] += val;
      else if (diff >= K_)  p64[r] += val;
      else cat[((size_t)(b * 256 + i)) * 1088 + h * 65 + diff + K_] = f2bf(val);
    }
  }
#pragma unroll
  for (int r = 0; r < 4; ++r)
#pragma unroll
    for (int o = 1; o < 16; o <<= 1) {
      p0[r]  += __shfl_xor(p0[r], o, 64);
      p64[r] += __shfl_xor(p64[r], o, 64);
    }
  if (lm == 0) {
#pragma unroll
    for (int r = 0; r < 4; ++r) {
      int i = ibase + r;
      cat[((size_t)(b * 256 + i)) * 1088 + h * 65 + 0]      = f2bf(p0[r]);
      cat[((size_t)(b * 256 + i)) * 1088 + h * 65 + 2 * K_] = f2bf(p64[r]);
    }
  }
  // interior bins with out-of-range source j -> 0
#pragma unroll
  for (int r = 0; r < 4; ++r) {
    int i = ibase + r;
#pragma unroll
    for (int t = 0; t < 4; ++t) {
      int c = 1 + lm + 16 * t;
      if (c < 64) {
        int j = i - c + K_;
        if (j < 0 || j > 255)
          cat[((size_t)(b * 256 + i)) * 1088 + h * 65 + c] = 0;
      }
    }
  }
  // pad cols 1032..1088 zeroed by h==0 blocks
  if (h == 0) {
    for (int idx = tid; idx < 32 * 56; idx += 128) {
      int r = idx / 56, c = 1032 + (idx - r * 56);
      cat[((size_t)(b * 256 + strip * 32 + r)) * 1088 + c] = 0;
    }
  }
  // ---- PV: o = P @ V over 4 k-quarters; V frags direct from global ----
  f32x4 acc2[4];
#pragma unroll
  for (int nt = 0; nt < 4; ++nt) acc2[nt] = (f32x4){0.f, 0.f, 0.f, 0.f};
  const ushort* vbase = vT + (size_t)bh * 16384;
#pragma unroll
  for (int qt = 0; qt < 4; ++qt) {
    bf16x8 vf0[4], vf1[4];
#pragma unroll
    for (int nt = 0; nt < 4; ++nt) {
      const ushort* vrow = vbase + (size_t)(nt * 16 + lm) * 256 + qt * 64 + lq * 8;
      vf0[nt] = *(const bf16x8*)vrow;
      vf1[nt] = *(const bf16x8*)(vrow + 32);
    }
#pragma unroll
    for (int ctl = 0; ctl < 4; ++ctl) {
      int ct = qt * 4 + ctl;
#pragma unroll
      for (int r = 0; r < 4; ++r) {
        int rowl = w * 16 + lq * 4 + r;
        int g = ctl * 2 + (lm >> 3);
        Ps[rowl * 64 + ((g ^ (rowl & 7)) << 3) + (lm & 7)] =
            f2bf(acc[ct][r] * sm[r]);
      }
    }
    int prow = w * 16 + lm;
#pragma unroll
    for (int kst = 0; kst < 2; ++kst) {
      bf16x8 af = *(const bf16x8*)&Ps[prow * 64 + (((kst * 4 + lq) ^ (prow & 7)) << 3)];
#pragma unroll
      for (int nt = 0; nt < 4; ++nt)
        acc2[nt] = __builtin_amdgcn_mfma_f32_16x16x32_bf16(
            af, kst ? vf1[nt] : vf0[nt], acc2[nt], 0, 0, 0);
    }
  }
#pragma unroll
  for (int nt = 0; nt < 4; ++nt) {
    int d = nt * 16 + lm;
#pragma unroll
    for (int r = 0; r < 4; ++r) {
      int i = ibase + r;
      cat[((size_t)(b * 256 + i)) * 1088 + 520 + h * 64 + d] = f2bf(acc2[nt][r]);
    }
  }
}

// ---------------- out = LayerNorm(x1 + sum_s xp_bf16[s]) * g + b ----------
__global__ __launch_bounds__(128) void ln_sum(
    const float* __restrict__ x1, const ushort* __restrict__ xp,
    int S, int stride, const float* __restrict__ g,
    const float* __restrict__ bta, float* __restrict__ out,
    __hip_bfloat16* __restrict__ out_bf) {
  __shared__ float redA[2], redB[2];
  int row = blockIdx.x, tid = threadIdx.x;
  size_t base = (size_t)row * 512;
  float4 v = *(const float4*)(x1 + base + tid * 4);
  for (int s = 0; s < S; ++s) {
    uint2 p = *(const uint2*)(xp + (size_t)s * stride + base + tid * 4);
    v.x += bf2f((ushort)(p.x & 0xffff));
    v.y += bf2f((ushort)(p.x >> 16));
    v.z += bf2f((ushort)(p.y & 0xffff));
    v.w += bf2f((ushort)(p.y >> 16));
  }
  float su = v.x + v.y + v.z + v.w;
  float sq = v.x * v.x + v.y * v.y + v.z * v.z + v.w * v.w;
#pragma unroll
  for (int o = 32; o > 0; o >>= 1) {
    su += __shfl_xor(su, o, 64);
    sq += __shfl_xor(sq, o, 64);
  }
  int w = tid >> 6;
  if ((tid & 63) == 0) { redA[w] = su; redB[w] = sq; }
  __syncthreads();
  su = redA[0] + redA[1]; sq = redB[0] + redB[1];
  float mean = su * (1.f / 512.f);
  float var = sq * (1.f / 512.f) - mean * mean;
  float inv = rsqrtf(var + 1e-5f);
  float4 gv = *(const float4*)(g + tid * 4);
  float4 bv = *(const float4*)(bta + tid * 4);
  float4 o4;
  o4.x = (v.x - mean) * inv * gv.x + bv.x;
  o4.y = (v.y - mean) * inv * gv.y + bv.y;
  o4.z = (v.z - mean) * inv * gv.z + bv.z;
  o4.w = (v.w - mean) * inv * gv.w + bv.w;
  *(float4*)(out + base + tid * 4) = o4;
  if (out_bf) {
    ushort pk[4] = {f2bf(o4.x), f2bf(o4.y), f2bf(o4.z), f2bf(o4.w)};
    *(uint2*)&((ushort*)out_bf)[base + tid * 4] = *(uint2*)pk;
  }
}

extern "C" void kernel_launch(void* const* d_in, const int* in_sizes, int n_in,
                              void* d_out, int out_size, void* d_ws, size_t ws_size,
                              hipStream_t stream) {
  const float* s     = (const float*)d_in[0];
  const int*   masks = (const int*)d_in[1];
  const float* wq = (const float*)d_in[2];
  const float* wk = (const float*)d_in[3];
  const float* wv = (const float*)d_in[4];
  const float* wb = (const float*)d_in[5];
  const float* wo = (const float*)d_in[6];
  const float* bo = (const float*)d_in[7];
  const float* ln1_g = (const float*)d_in[8];
  const float* ln1_b = (const float*)d_in[9];
  const float* w1 = (const float*)d_in[10];
  const float* b1 = (const float*)d_in[11];
  const float* w2 = (const float*)d_in[12];
  const float* b2 = (const float*)d_in[13];
  const float* ln2_g = (const float*)d_in[14];
  const float* ln2_b = (const float*)d_in[15];

  float* out_x = (float*)d_out;              // [8,256,512]
  float* out_a = out_x + 1048576;            // [8,8,256,256]

  // disjoint workspace (float offsets)
  float* ws = (float*)d_ws;
  ushort* embd_part = (ushort*)(ws + 0);                   // [2][2048,512] bf16
  float* xbuf       = ws + 4194304;
  ushort* ff_part   = (ushort*)(ws + 5242880);             // [2][2048,512] bf16
  ushort* qkv_bf    = (ushort*)(ws + 9437184);             // q|k [B,H,N,D], v [B,H,D,N]
  ushort* q_bf = qkv_bf;
  ushort* k_bf = qkv_bf + 1048576;
  ushort* v_bf = qkv_bf + 2097152;
  ushort* cat_bf = (ushort*)(ws + 10223616);               // [2048,1088]
  __hip_bfloat16* h_bf  = (__hip_bfloat16*)(ws + 11337728);  // [2048,2048]
  __hip_bfloat16* s_bf  = (__hip_bfloat16*)(ws + 13434880);  // [2048,512]
  __hip_bfloat16* x_bf  = (__hip_bfloat16*)(ws + 13959168);  // [2048,512]
  __hip_bfloat16* wqkvT = (__hip_bfloat16*)(ws + 14483456);  // [1536,512]
  ushort* wopT  = (ushort*)(ws + 14876672);                // [512,1088]
  ushort* w1T   = (ushort*)(ws + 15155200);                // [2048,512]
  ushort* w2T   = (ushort*)(ws + 15679488);                // [512,2048]

  dim3 blkg(128);
  // 0. prep: s cvt (512 blocks) + wqkv transpose (768 blocks)
  prep_small<<<dim3(1280), dim3(256), 0, stream>>>(s, s_bf, wq, wk, wv, wqkvT);
  // 1. QKV projection (768 gemm blocks) + wo/w1/w2 transposes (2592 blocks)
  qkvT<<<dim3(3360), blkg, 0, stream>>>(
      (const ushort*)s_bf, (const ushort*)wqkvT, qkv_bf,
      wo, w1, w2, wopT, w1T, w2T);
  // 2. fused attention: a -> d_out, o + o_pair -> cat_bf  [512 x 128thr]
  attn_fused<<<dim3(512), blkg, 0, stream>>>(q_bf, k_bf, v_bf, masks, wb,
                                             out_a, cat_bf);
  // 3. output projection (split-K=2, bf16 partials)  [512 blocks]
  gemm_bf16<<<dim3(8, 32, 2), blkg, 0, stream>>>(
      cat_bf, wopT, bo, nullptr, embd_part, 2048, 512, 1088, 1 | 4 | 32);
  // 4. x = LN(s + sum embd_part)
  ln_sum<<<dim3(2048), blkg, 0, stream>>>(s, embd_part, 2, 1048576,
                                          ln1_g, ln1_b, xbuf, x_bf);
  // 5. FFN1  [1024 blocks]
  gemm_bf16<<<dim3(32, 32, 1), blkg, 0, stream>>>(
      (const ushort*)x_bf, w1T, b1, nullptr, (ushort*)h_bf,
      2048, 2048, 512, 1 | 2 | 4);
  // 6. FFN2 (split-K=2)  [512 blocks]
  gemm_bf16<<<dim3(8, 32, 2), blkg, 0, stream>>>(
      (const ushort*)h_bf, w2T, b2, nullptr, ff_part,
      2048, 512, 2048, 1 | 4 | 32);
  // 7. out = LN(x + sum ff_part)
  ln_sum<<<dim3(2048), blkg, 0, stream>>>(xbuf, ff_part, 2, 1048576,
                                          ln2_g, ln2_b, out_x, nullptr);
}